// Round 2
// baseline (476.690 us; speedup 1.0000x reference)
//
#include <hip/hip_runtime.h>
#include <hip/hip_bf16.h>

// Problem constants (from reference)
#define DFEAT   64
#define NREL    8
#define KDIM    512     // DFEAT * NREL
#define DOUT    64
#define NBASES  4

#define NC      256     // dst chunks (one slab + one aggregate block each)
#define EPB     2048    // edges per binning block (256 thr x 8)
#define CAPB    12      // LDS bin slots/chunk; mean 8, overflow -> direct append
#define SPAN    196     // node span per aggregate block; SPAN*64*4B = 50 KB LDS

typedef short short8 __attribute__((ext_vector_type(8)));    // 8 bf16 = 4 VGPRs
typedef float f32x4  __attribute__((ext_vector_type(4)));    // MFMA C/D frag
typedef unsigned short ushort8 __attribute__((ext_vector_type(8)));  // 16B

// fp32 -> bf16 round-to-nearest-even (bit pattern)
__device__ __forceinline__ unsigned short f2bf(float f) {
    unsigned u = __float_as_uint(f);
    u += 0x7fff + ((u >> 16) & 1);
    return (unsigned short)(u >> 16);
}
__device__ __forceinline__ float bf2f(unsigned short b) {
    return __uint_as_float(((unsigned)b) << 16);
}

// ---------------------------------------------------------------------------
// K1: wT[o][k] = bf16( sum_b w_rel[r,b] * w_bases[b,i,o] ),  k = i*8+r.
// Also zeros the 256 chunk cursors + overflow cursor.
// ---------------------------------------------------------------------------
__global__ __launch_bounds__(256) void weight_kernel(
    const float* __restrict__ w_rel,    // [NREL][NBASES]
    const float* __restrict__ w_bases,  // [NBASES][DFEAT][DOUT]
    unsigned short* __restrict__ wT,    // [DOUT][KDIM] bf16 bits
    int* __restrict__ cursor)
{
    int idx = blockIdx.x * 256 + threadIdx.x;   // 0..32767
    int k = idx & 511;     // i*8 + r
    int o = idx >> 9;      // 0..63
    int i = k >> 3;
    int r = k & 7;
    float s = 0.f;
#pragma unroll
    for (int b = 0; b < NBASES; ++b)
        s += w_rel[r * NBASES + b] * w_bases[(b * DFEAT + i) * DOUT + o];
    wT[o * KDIM + k] = f2bf(s);

    if (idx < NC + 8) cursor[idx] = 0;
}

// LDS overlay: transform blocks use ylds, binning blocks use b. (~28 KB)
union SharedK2 {
    unsigned short ylds[4][16][64];            // 8 KB
    struct {
        uint2 bin[NC][CAPB];                   // 24 KB
        int bcnt[NC];                          // 1 KB
    } b;
};

// ---------------------------------------------------------------------------
// Fused K2: grid-partitioned.
//   blocks [0, t_blocks):   transform  Y = Xflat @ Wflat via bf16 MFMA
//     (one wave = 16 nodes x 64 outs), LDS-staged coalesced epilogue.
//   blocks [t_blocks, ..):  BIN — stage EPB edges into 256 LDS bins by
//     dst-chunk (low per-address LDS-atomic contention: mean 8 edges/bin),
//     then flush one-thread-per-bin: one cursor atomic + serial appends
//     into the per-chunk slab (lines assembled append-style, written once).
//     Bin/slab overflow falls back to per-record cursor append / overflow
//     list, so correctness is distribution- and ws-size-independent.
// ---------------------------------------------------------------------------
__global__ __launch_bounds__(256) void fused_kernel(
    const float* __restrict__ x,    // [n_nodes][KDIM] fp32
    const unsigned short* __restrict__ wT,   // [DOUT][KDIM] bf16
    unsigned short* __restrict__ y, // [n_nodes][DOUT] bf16
    int n_nodes,
    const int* __restrict__ esrc, const int* __restrict__ edst,
    const float* __restrict__ ew,
    int* __restrict__ cursor,
    uint2* __restrict__ slab, uint2* __restrict__ ovf,
    int n_edges, int chsz, int slab_cap, int ovf_cap, int t_blocks)
{
    const int tid = threadIdx.x;
    __shared__ SharedK2 sh;

    if (blockIdx.x >= t_blocks) {
        // ---- bin phase ----
        auto& B = sh.b;
        B.bcnt[tid] = 0;           // 256 threads == NC
        __syncthreads();

        int e0 = (blockIdx.x - t_blocks) * EPB + tid;
#pragma unroll
        for (int j = 0; j < EPB / 256; ++j) {
            int e = e0 + j * 256;
            if (e < n_edges) {
                int d = edst[e];
                unsigned entry = (unsigned)(esrc[e] & 0xFFFF)
                               | ((unsigned)f2bf(ew[e]) << 16);
                int c = d / chsz;                       // 0..NC-1
                uint2 rec = make_uint2(entry, (unsigned)d);
                int pos = atomicAdd(&B.bcnt[c], 1);
                if (pos < CAPB) {
                    B.bin[c][pos] = rec;
                } else {  // LDS bin overflow (~2% of records): direct append
                    int p = atomicAdd(&cursor[c], 1);
                    if (p < slab_cap) slab[(size_t)c * slab_cap + p] = rec;
                    else { int q = atomicAdd(&cursor[NC], 1);
                           if (q < ovf_cap) ovf[q] = rec; }
                }
            }
        }
        __syncthreads();

        // ---- flush: one thread per bin ----
        {
            int c = tid;
            int n = B.bcnt[c]; if (n > CAPB) n = CAPB;
            int bb = atomicAdd(&cursor[c], n);
            uint2* sc = slab + (size_t)c * slab_cap;
            for (int i = 0; i < n; ++i) {
                uint2 rec = B.bin[c][i];
                int p = bb + i;
                if (p < slab_cap) sc[p] = rec;
                else { int q = atomicAdd(&cursor[NC], 1);
                       if (q < ovf_cap) ovf[q] = rec; }
            }
        }
        return;
    }

    // ---- transform phase ----
    const int wid  = tid >> 6;
    const int lane = tid & 63;
    const int quad = lane >> 4;    // 0..3
    const int fi   = lane & 15;    // 0..15

    const int node0 = (blockIdx.x * 4 + wid) * 16;
    int myrow = node0 + fi;
    if (myrow >= n_nodes) myrow = n_nodes - 1;
    const float* xg = x + (size_t)myrow * KDIM + quad * 8;
    const unsigned short* wg = wT + fi * KDIM + quad * 8;

    f32x4 acc0 = {0.f, 0.f, 0.f, 0.f};
    f32x4 acc1 = {0.f, 0.f, 0.f, 0.f};
    f32x4 acc2 = {0.f, 0.f, 0.f, 0.f};
    f32x4 acc3 = {0.f, 0.f, 0.f, 0.f};

#pragma unroll 4
    for (int kb = 0; kb < KDIM; kb += 32) {
        float4 xa = *(const float4*)(xg + kb);
        float4 xb = *(const float4*)(xg + kb + 4);
        short8 a;
        a[0] = f2bf(xa.x); a[1] = f2bf(xa.y); a[2] = f2bf(xa.z); a[3] = f2bf(xa.w);
        a[4] = f2bf(xb.x); a[5] = f2bf(xb.y); a[6] = f2bf(xb.z); a[7] = f2bf(xb.w);

        short8 b0 = *(const short8*)(wg + kb);
        short8 b1 = *(const short8*)(wg + 16 * KDIM + kb);
        short8 b2 = *(const short8*)(wg + 32 * KDIM + kb);
        short8 b3 = *(const short8*)(wg + 48 * KDIM + kb);

        acc0 = __builtin_amdgcn_mfma_f32_16x16x32_bf16(a, b0, acc0, 0, 0, 0);
        acc1 = __builtin_amdgcn_mfma_f32_16x16x32_bf16(a, b1, acc1, 0, 0, 0);
        acc2 = __builtin_amdgcn_mfma_f32_16x16x32_bf16(a, b2, acc2, 0, 0, 0);
        acc3 = __builtin_amdgcn_mfma_f32_16x16x32_bf16(a, b3, acc3, 0, 0, 0);
    }

    // epilogue: C layout col=fi, row=quad*4+r -> stage to LDS, store b128
#pragma unroll
    for (int r = 0; r < 4; ++r) {
        int n = quad * 4 + r;
        sh.ylds[wid][n][fi]      = f2bf(acc0[r]);
        sh.ylds[wid][n][16 + fi] = f2bf(acc1[r]);
        sh.ylds[wid][n][32 + fi] = f2bf(acc2[r]);
        sh.ylds[wid][n][48 + fi] = f2bf(acc3[r]);
    }
    __syncthreads();   // uniform: no transform wave returned early

    int nl = lane >> 2;            // node_local 0..15
    int cg = (lane & 3) * 16;      // 16-short chunk within the 64-col row
    int node = node0 + nl;
    if (node < n_nodes) {
        ushort8 v0 = *(const ushort8*)&sh.ylds[wid][nl][cg];
        ushort8 v1 = *(const ushort8*)&sh.ylds[wid][nl][cg + 8];
        unsigned short* yr = y + (size_t)node * DOUT + cg;
        *(ushort8*)yr       = v0;
        *(ushort8*)(yr + 8) = v1;
    }
}

// ---------------------------------------------------------------------------
// K3: aggregate — merged scatter+gather. One block per (chunk, sub-span):
// fp32 accumulator acc[SPAN][64] in LDS; scan the chunk slab ONCE with
// uniform (scalar) 8B record loads; per record: wave-wide y[src] row load
// (128B, L2-resident) + wave-wide ds_add_f32 (2-way bank = free).
// out written once, coalesced, from LDS. No bucket, no cnt, no rescans.
// ---------------------------------------------------------------------------
__global__ __launch_bounds__(1024) void aggregate_kernel(
    const uint2* __restrict__ slab, const uint2* __restrict__ ovf,
    const int* __restrict__ cursor,
    const unsigned short* __restrict__ y,
    float* __restrict__ out, int n_nodes, int chsz, int nsub,
    int slab_cap, int ovf_cap)
{
    __shared__ float acc[SPAN * DOUT];     // 50176 B
    const int tid = threadIdx.x;
    const int c = blockIdx.x / nsub;       // chunk
    const int s = blockIdx.x % nsub;       // sub-span (nsub==1 for N=50k)
    const int nbase = c * chsz + s * SPAN;
    int nspan = SPAN;
    if (nspan > chsz - s * SPAN)  nspan = chsz - s * SPAN;
    if (nspan > n_nodes - nbase)  nspan = n_nodes - nbase;
    if (nspan <= 0) return;                // uniform: before any sync

    for (int i = tid; i < nspan * DOUT; i += 1024) acc[i] = 0.f;
    __syncthreads();

    const int lane = tid & 63;
    const int wv   = tid >> 6;             // 0..15
    int total = cursor[c]; if (total > slab_cap) total = slab_cap;
    const uint2* sl = slab + (size_t)c * slab_cap;
    int per  = (total + 15) >> 4;          // contiguous slice per wave
    int rbeg = wv * per;
    int rend = rbeg + per; if (rend > total) rend = total;
    const unsigned short* yl = y + lane;

#pragma unroll 4
    for (int i = rbeg; i < rend; ++i) {
        uint2 rec = sl[i];                 // wave-uniform addr -> scalar load
        int rel = (int)rec.y - nbase;
        if ((unsigned)rel < (unsigned)nspan) {   // wave-uniform branch
            float w = __uint_as_float(rec.x & 0xFFFF0000u);
            int src = (int)(rec.x & 0xFFFFu);
            atomicAdd(&acc[rel * DOUT + lane],
                      w * bf2f(yl[(size_t)src * DOUT]));
        }
    }

    // overflow records (expected ~0): per-thread slow path
    int novf = cursor[NC]; if (novf > ovf_cap) novf = ovf_cap;
    for (int i = tid; i < novf; i += 1024) {
        uint2 rec = ovf[i];
        int rel = (int)rec.y - nbase;
        if ((unsigned)rel < (unsigned)nspan) {
            float w = __uint_as_float(rec.x & 0xFFFF0000u);
            int src = (int)(rec.x & 0xFFFFu);
            for (int j = 0; j < DOUT; ++j)
                atomicAdd(&acc[rel * DOUT + j],
                          w * bf2f(y[(size_t)src * DOUT + j]));
        }
    }
    __syncthreads();

    float4* o4 = (float4*)(out + (size_t)nbase * DOUT);
    const float4* a4 = (const float4*)acc;
    for (int i = tid; i < nspan * (DOUT / 4); i += 1024) o4[i] = a4[i];
}

extern "C" void kernel_launch(void* const* d_in, const int* in_sizes, int n_in,
                              void* d_out, int out_size, void* d_ws, size_t ws_size,
                              hipStream_t stream) {
    const float* x       = (const float*)d_in[0];
    const int*   esrc    = (const int*)d_in[1];
    const int*   edst    = (const int*)d_in[2];
    const float* ew      = (const float*)d_in[3];
    const float* w_bases = (const float*)d_in[4];
    const float* w_rel   = (const float*)d_in[5];
    float* out = (float*)d_out;

    const int n_nodes = in_sizes[0] / KDIM;   // 50000 (< 65536: src fits 16 bits)
    const int n_edges = in_sizes[1];
    const int chsz = (n_nodes + NC - 1) / NC;        // 196
    const int nsub = (chsz + SPAN - 1) / SPAN;       // 1 for N=50k

    // Workspace (4-byte words):
    // y bf16: n*32 | wT: 16384 | cursor: 264 | slab: NC*slab_cap*2 | ovf
    size_t wsw = ws_size / 4;
    size_t base = (size_t)n_nodes * 32 + 16384 + 264;
    size_t avail = (wsw > base) ? wsw - base : 0;
    size_t slab_budget = avail * 7 / 8;
    int slab_cap = (int)(slab_budget / (2 * NC));
    if (slab_cap > 4096) slab_cap = 4096;     // mean 3125/chunk, +17 sigma
    size_t ovf_words = avail - (size_t)2 * NC * slab_cap;
    size_t oc = ovf_words / 2;
    int ovf_cap = (int)(oc > (size_t)n_edges ? (size_t)n_edges : oc);

    unsigned short* y   = (unsigned short*)d_ws;
    unsigned short* wT  = y + (size_t)n_nodes * DOUT;
    int*   cursor       = (int*)(wT + KDIM * DOUT);
    uint2* slab         = (uint2*)(cursor + 264);     // even word offset: 8B ok
    uint2* ovf          = slab + (size_t)NC * slab_cap;

    weight_kernel<<<(KDIM * DOUT) / 256, 256, 0, stream>>>(
        w_rel, w_bases, wT, cursor);

    const int t_blocks = (n_nodes + 63) / 64;          // 4 waves x 16 nodes
    const int p_blocks = (n_edges + EPB - 1) / EPB;    // binning blocks
    fused_kernel<<<t_blocks + p_blocks, 256, 0, stream>>>(
        x, wT, y, n_nodes,
        esrc, edst, ew, cursor, slab, ovf,
        n_edges, chsz, slab_cap, ovf_cap, t_blocks);

    aggregate_kernel<<<NC * nsub, 1024, 0, stream>>>(
        slab, ovf, cursor, y, out, n_nodes, chsz, nsub, slab_cap, ovf_cap);
}

// Round 3
// 464.511 us; speedup vs baseline: 1.0262x; 1.0262x over previous
//
#include <hip/hip_runtime.h>
#include <hip/hip_bf16.h>

// Problem constants (from reference)
#define DFEAT   64
#define NREL    8
#define KDIM    512     // DFEAT * NREL
#define DOUT    64
#define NBASES  4

#define NC      256     // dst chunks (one slab + one aggregate block each)
#define EPB     2048    // edges per binning block (256 thr x 8)
#define CAPB    12      // LDS bin slots/chunk; mean 8, overflow -> direct append
#define SPAN    196     // node span per aggregate block; SPAN*64*4B = 50 KB LDS
#define RPG     16      // records in flight per wave (the ILP fix)

typedef short short8 __attribute__((ext_vector_type(8)));    // 8 bf16 = 4 VGPRs
typedef float f32x4  __attribute__((ext_vector_type(4)));    // MFMA C/D frag
typedef unsigned short ushort8 __attribute__((ext_vector_type(8)));  // 16B

// fp32 -> bf16 round-to-nearest-even (bit pattern)
__device__ __forceinline__ unsigned short f2bf(float f) {
    unsigned u = __float_as_uint(f);
    u += 0x7fff + ((u >> 16) & 1);
    return (unsigned short)(u >> 16);
}
__device__ __forceinline__ float bf2f(unsigned short b) {
    return __uint_as_float(((unsigned)b) << 16);
}

// ---------------------------------------------------------------------------
// K1: wT[o][k] = bf16( sum_b w_rel[r,b] * w_bases[b,i,o] ),  k = i*8+r.
// Also zeros the 256 chunk cursors + overflow cursor.
// ---------------------------------------------------------------------------
__global__ __launch_bounds__(256) void weight_kernel(
    const float* __restrict__ w_rel,    // [NREL][NBASES]
    const float* __restrict__ w_bases,  // [NBASES][DFEAT][DOUT]
    unsigned short* __restrict__ wT,    // [DOUT][KDIM] bf16 bits
    int* __restrict__ cursor)
{
    int idx = blockIdx.x * 256 + threadIdx.x;   // 0..32767
    int k = idx & 511;     // i*8 + r
    int o = idx >> 9;      // 0..63
    int i = k >> 3;
    int r = k & 7;
    float s = 0.f;
#pragma unroll
    for (int b = 0; b < NBASES; ++b)
        s += w_rel[r * NBASES + b] * w_bases[(b * DFEAT + i) * DOUT + o];
    wT[o * KDIM + k] = f2bf(s);

    if (idx < NC + 8) cursor[idx] = 0;
}

// LDS overlay: transform blocks use ylds, binning blocks use b. (~28 KB)
union SharedK2 {
    unsigned short ylds[4][16][64];            // 8 KB
    struct {
        uint2 bin[NC][CAPB];                   // 24 KB
        int bcnt[NC];                          // 1 KB
    } b;
};

// ---------------------------------------------------------------------------
// Fused K2: grid-partitioned. (unchanged from round 2 — measured ~62 us)
//   blocks [0, t_blocks):   transform  Y = Xflat @ Wflat via bf16 MFMA
//   blocks [t_blocks, ..):  BIN — 256 LDS bins by dst-chunk, flushed
//     one-thread-per-bin into per-chunk slabs; per-record fallback keeps
//     correctness distribution/ws-size independent.
// ---------------------------------------------------------------------------
__global__ __launch_bounds__(256) void fused_kernel(
    const float* __restrict__ x,    // [n_nodes][KDIM] fp32
    const unsigned short* __restrict__ wT,   // [DOUT][KDIM] bf16
    unsigned short* __restrict__ y, // [n_nodes][DOUT] bf16
    int n_nodes,
    const int* __restrict__ esrc, const int* __restrict__ edst,
    const float* __restrict__ ew,
    int* __restrict__ cursor,
    uint2* __restrict__ slab, uint2* __restrict__ ovf,
    int n_edges, int chsz, int slab_cap, int ovf_cap, int t_blocks)
{
    const int tid = threadIdx.x;
    __shared__ SharedK2 sh;

    if (blockIdx.x >= t_blocks) {
        // ---- bin phase ----
        auto& B = sh.b;
        B.bcnt[tid] = 0;           // 256 threads == NC
        __syncthreads();

        int e0 = (blockIdx.x - t_blocks) * EPB + tid;
#pragma unroll
        for (int j = 0; j < EPB / 256; ++j) {
            int e = e0 + j * 256;
            if (e < n_edges) {
                int d = edst[e];
                unsigned entry = (unsigned)(esrc[e] & 0xFFFF)
                               | ((unsigned)f2bf(ew[e]) << 16);
                int c = d / chsz;                       // 0..NC-1
                uint2 rec = make_uint2(entry, (unsigned)d);
                int pos = atomicAdd(&B.bcnt[c], 1);
                if (pos < CAPB) {
                    B.bin[c][pos] = rec;
                } else {  // LDS bin overflow (~2% of records): direct append
                    int p = atomicAdd(&cursor[c], 1);
                    if (p < slab_cap) slab[(size_t)c * slab_cap + p] = rec;
                    else { int q = atomicAdd(&cursor[NC], 1);
                           if (q < ovf_cap) ovf[q] = rec; }
                }
            }
        }
        __syncthreads();

        // ---- flush: one thread per bin ----
        {
            int c = tid;
            int n = B.bcnt[c]; if (n > CAPB) n = CAPB;
            int bb = atomicAdd(&cursor[c], n);
            uint2* sc = slab + (size_t)c * slab_cap;
            for (int i = 0; i < n; ++i) {
                uint2 rec = B.bin[c][i];
                int p = bb + i;
                if (p < slab_cap) sc[p] = rec;
                else { int q = atomicAdd(&cursor[NC], 1);
                       if (q < ovf_cap) ovf[q] = rec; }
            }
        }
        return;
    }

    // ---- transform phase ----
    const int wid  = tid >> 6;
    const int lane = tid & 63;
    const int quad = lane >> 4;    // 0..3
    const int fi   = lane & 15;    // 0..15

    const int node0 = (blockIdx.x * 4 + wid) * 16;
    int myrow = node0 + fi;
    if (myrow >= n_nodes) myrow = n_nodes - 1;
    const float* xg = x + (size_t)myrow * KDIM + quad * 8;
    const unsigned short* wg = wT + fi * KDIM + quad * 8;

    f32x4 acc0 = {0.f, 0.f, 0.f, 0.f};
    f32x4 acc1 = {0.f, 0.f, 0.f, 0.f};
    f32x4 acc2 = {0.f, 0.f, 0.f, 0.f};
    f32x4 acc3 = {0.f, 0.f, 0.f, 0.f};

#pragma unroll 4
    for (int kb = 0; kb < KDIM; kb += 32) {
        float4 xa = *(const float4*)(xg + kb);
        float4 xb = *(const float4*)(xg + kb + 4);
        short8 a;
        a[0] = f2bf(xa.x); a[1] = f2bf(xa.y); a[2] = f2bf(xa.z); a[3] = f2bf(xa.w);
        a[4] = f2bf(xb.x); a[5] = f2bf(xb.y); a[6] = f2bf(xb.z); a[7] = f2bf(xb.w);

        short8 b0 = *(const short8*)(wg + kb);
        short8 b1 = *(const short8*)(wg + 16 * KDIM + kb);
        short8 b2 = *(const short8*)(wg + 32 * KDIM + kb);
        short8 b3 = *(const short8*)(wg + 48 * KDIM + kb);

        acc0 = __builtin_amdgcn_mfma_f32_16x16x32_bf16(a, b0, acc0, 0, 0, 0);
        acc1 = __builtin_amdgcn_mfma_f32_16x16x32_bf16(a, b1, acc1, 0, 0, 0);
        acc2 = __builtin_amdgcn_mfma_f32_16x16x32_bf16(a, b2, acc2, 0, 0, 0);
        acc3 = __builtin_amdgcn_mfma_f32_16x16x32_bf16(a, b3, acc3, 0, 0, 0);
    }

    // epilogue: C layout col=fi, row=quad*4+r -> stage to LDS, store b128
#pragma unroll
    for (int r = 0; r < 4; ++r) {
        int n = quad * 4 + r;
        sh.ylds[wid][n][fi]      = f2bf(acc0[r]);
        sh.ylds[wid][n][16 + fi] = f2bf(acc1[r]);
        sh.ylds[wid][n][32 + fi] = f2bf(acc2[r]);
        sh.ylds[wid][n][48 + fi] = f2bf(acc3[r]);
    }
    __syncthreads();   // uniform: no transform wave returned early

    int nl = lane >> 2;            // node_local 0..15
    int cg = (lane & 3) * 16;      // 16-short chunk within the 64-col row
    int node = node0 + nl;
    if (node < n_nodes) {
        ushort8 v0 = *(const ushort8*)&sh.ylds[wid][nl][cg];
        ushort8 v1 = *(const ushort8*)&sh.ylds[wid][nl][cg + 8];
        unsigned short* yr = y + (size_t)node * DOUT + cg;
        *(ushort8*)yr       = v0;
        *(ushort8*)(yr + 8) = v1;
    }
}

// ---------------------------------------------------------------------------
// K3: aggregate — one block per (chunk, sub-span), fp32 acc[SPAN][64] in LDS.
// ILP fix vs round 2: each wave scans its share of the chunk slab in groups
// of RPG=16 records: 16 wave-uniform record loads (scalar, all in flight),
// then 16 independent wave-wide y-row loads (lane=feature), then 16
// conflict-free ds_add_f32. Critical path = ngrp/16 groups of overlapped
// latency instead of per-record serial chains.
// ---------------------------------------------------------------------------
__global__ __launch_bounds__(1024) void aggregate_kernel(
    const uint2* __restrict__ slab, const uint2* __restrict__ ovf,
    const int* __restrict__ cursor,
    const unsigned short* __restrict__ y,
    float* __restrict__ out, int n_nodes, int chsz, int nsub,
    int slab_cap, int ovf_cap)
{
    __shared__ float acc[SPAN * DOUT];     // 50176 B
    const int tid = threadIdx.x;
    const int c = blockIdx.x / nsub;       // chunk
    const int s = blockIdx.x % nsub;       // sub-span (nsub==1 for N=50k)
    const int nbase = c * chsz + s * SPAN;
    int nspan = SPAN;
    if (nspan > chsz - s * SPAN)  nspan = chsz - s * SPAN;
    if (nspan > n_nodes - nbase)  nspan = n_nodes - nbase;
    if (nspan <= 0) return;                // uniform: before any sync

    for (int i = tid; i < nspan * DOUT; i += 1024) acc[i] = 0.f;
    __syncthreads();

    const int lane = tid & 63;
    const int wv   = tid >> 6;             // 0..15
    int total = cursor[c]; if (total > slab_cap) total = slab_cap;
    const uint2* sl = slab + (size_t)c * slab_cap;
    const unsigned short* yl = y + lane;

    int ngrp = (total + RPG - 1) / RPG;
#pragma unroll 1
    for (int g = wv; g < ngrp; g += 16) {
        int base = g * RPG;
        int m = total - base; if (m > RPG) m = RPG;

        unsigned rx[RPG]; int rl[RPG];
#pragma unroll
        for (int r = 0; r < RPG; ++r) {      // 16 scalar loads, independent
            uint2 rec = sl[base + (r < m ? r : 0)];
            rx[r] = rec.x;
            rl[r] = (r < m) ? ((int)rec.y - nbase) : -1;
        }
        float yv[RPG];
#pragma unroll
        for (int r = 0; r < RPG; ++r) {      // 16 wave-wide y rows in flight
            int src = (int)(rx[r] & 0xFFFFu);
            yv[r] = bf2f(yl[(size_t)src * DOUT]);
        }
#pragma unroll
        for (int r = 0; r < RPG; ++r) {      // 16 conflict-free ds_add_f32
            if ((unsigned)rl[r] < (unsigned)nspan) {
                float w = __uint_as_float(rx[r] & 0xFFFF0000u);
                atomicAdd(&acc[rl[r] * DOUT + lane], w * yv[r]);
            }
        }
    }

    // overflow records (expected ~0): per-thread slow path
    int novf = cursor[NC]; if (novf > ovf_cap) novf = ovf_cap;
    for (int i = tid; i < novf; i += 1024) {
        uint2 rec = ovf[i];
        int rel = (int)rec.y - nbase;
        if ((unsigned)rel < (unsigned)nspan) {
            float w = __uint_as_float(rec.x & 0xFFFF0000u);
            int src = (int)(rec.x & 0xFFFFu);
            for (int j = 0; j < DOUT; ++j)
                atomicAdd(&acc[rel * DOUT + j],
                          w * bf2f(y[(size_t)src * DOUT + j]));
        }
    }
    __syncthreads();

    float4* o4 = (float4*)(out + (size_t)nbase * DOUT);
    const float4* a4 = (const float4*)acc;
    for (int i = tid; i < nspan * (DOUT / 4); i += 1024) o4[i] = a4[i];
}

extern "C" void kernel_launch(void* const* d_in, const int* in_sizes, int n_in,
                              void* d_out, int out_size, void* d_ws, size_t ws_size,
                              hipStream_t stream) {
    const float* x       = (const float*)d_in[0];
    const int*   esrc    = (const int*)d_in[1];
    const int*   edst    = (const int*)d_in[2];
    const float* ew      = (const float*)d_in[3];
    const float* w_bases = (const float*)d_in[4];
    const float* w_rel   = (const float*)d_in[5];
    float* out = (float*)d_out;

    const int n_nodes = in_sizes[0] / KDIM;   // 50000 (< 65536: src fits 16 bits)
    const int n_edges = in_sizes[1];
    const int chsz = (n_nodes + NC - 1) / NC;        // 196
    const int nsub = (chsz + SPAN - 1) / SPAN;       // 1 for N=50k

    // Workspace (4-byte words):
    // y bf16: n*32 | wT: 16384 | cursor: 264 | slab: NC*slab_cap*2 | ovf
    size_t wsw = ws_size / 4;
    size_t base = (size_t)n_nodes * 32 + 16384 + 264;
    size_t avail = (wsw > base) ? wsw - base : 0;
    size_t slab_budget = avail * 7 / 8;
    int slab_cap = (int)(slab_budget / (2 * NC));
    if (slab_cap > 4096) slab_cap = 4096;     // mean 3125/chunk, +17 sigma
    size_t ovf_words = avail - (size_t)2 * NC * slab_cap;
    size_t oc = ovf_words / 2;
    int ovf_cap = (int)(oc > (size_t)n_edges ? (size_t)n_edges : oc);

    unsigned short* y   = (unsigned short*)d_ws;
    unsigned short* wT  = y + (size_t)n_nodes * DOUT;
    int*   cursor       = (int*)(wT + KDIM * DOUT);
    uint2* slab         = (uint2*)(cursor + 264);     // even word offset: 8B ok
    uint2* ovf          = slab + (size_t)NC * slab_cap;

    weight_kernel<<<(KDIM * DOUT) / 256, 256, 0, stream>>>(
        w_rel, w_bases, wT, cursor);

    const int t_blocks = (n_nodes + 63) / 64;          // 4 waves x 16 nodes
    const int p_blocks = (n_edges + EPB - 1) / EPB;    // binning blocks
    fused_kernel<<<t_blocks + p_blocks, 256, 0, stream>>>(
        x, wT, y, n_nodes,
        esrc, edst, ew, cursor, slab, ovf,
        n_edges, chsz, slab_cap, ovf_cap, t_blocks);

    aggregate_kernel<<<NC * nsub, 1024, 0, stream>>>(
        slab, ovf, cursor, y, out, n_nodes, chsz, nsub, slab_cap, ovf_cap);
}